// Round 2
// baseline (17.951 us; speedup 1.0000x reference)
//
#include <hip/hip_runtime.h>

// Attentionlayer: B=4, T=12, N=1024, F_IN=64, F_OUT=64.
//
// Identity (verified R0, absmax 1.6e-2 vs threshold 1.5e-1):
//   sum(softmax(att, axis=3), axis=3) == 1 for every row, so
//   res = leaky_relu(h * 1) = leaky_relu(x @ W).
//
// R1 design: lane = output column (64 cols == wave width).
//  - W column per lane in 64 VGPRs (coalesced per-k dword loads).
//  - Each wave owns 16 rows; x reads are wave-uniform broadcasts
//    (1-2 cache lines per instruction, zero redundancy).
//  - k-chunk outer / row inner: 16 independent FMA chains.
//  - Stores coalesced: out[row][lane] = 256 B contiguous per instr.

constexpr int K    = 64;             // F_IN
constexpr int C    = 64;             // F_OUT
constexpr int ROWS = 4 * 12 * 1024;  // 49152
constexpr int RPW  = 16;             // rows per wave
constexpr int WVS  = 4;              // waves per block

__global__ __launch_bounds__(256) void gat_fused_kernel(
    const float* __restrict__ x, const float* __restrict__ W,
    float* __restrict__ out) {
  const int lane = threadIdx.x & 63;  // output column
  const int wid  = threadIdx.x >> 6;  // wave id, uniform within wave
  const int row0 = __builtin_amdgcn_readfirstlane(
      (int)blockIdx.x * (RPW * WVS) + wid * RPW);

  // Preload this lane's W column: W[k][lane], coalesced across lanes.
  float wc[K];
#pragma unroll
  for (int k = 0; k < K; ++k) wc[k] = W[k * C + lane];

  float acc[RPW];
#pragma unroll
  for (int r = 0; r < RPW; ++r) acc[r] = 0.f;

  const float* xb = x + (size_t)row0 * K;

  // Both loops fully unrolled: wc/acc must be compile-time indexed
  // (runtime-indexed register arrays spill to scratch on gfx950).
#pragma unroll
  for (int kq = 0; kq < K / 4; ++kq) {
#pragma unroll
    for (int r = 0; r < RPW; ++r) {
      float4 v = reinterpret_cast<const float4*>(xb + r * K)[kq];  // uniform
      acc[r] = fmaf(v.x, wc[4 * kq + 0], acc[r]);
      acc[r] = fmaf(v.y, wc[4 * kq + 1], acc[r]);
      acc[r] = fmaf(v.z, wc[4 * kq + 2], acc[r]);
      acc[r] = fmaf(v.w, wc[4 * kq + 3], acc[r]);
    }
  }

  // leaky_relu (slope 0.01) + coalesced dword stores (256 B/instr).
  float* ob = out + (size_t)row0 * C + lane;
#pragma unroll
  for (int r = 0; r < RPW; ++r) {
    float a = acc[r];
    ob[r * C] = a > 0.f ? a : 0.01f * a;
  }
}

extern "C" void kernel_launch(void* const* d_in, const int* in_sizes, int n_in,
                              void* d_out, int out_size, void* d_ws, size_t ws_size,
                              hipStream_t stream) {
  // setup_inputs order: x, adj, W, a. Only x and W matter (see identity).
  const float* x = (const float*)d_in[0];
  const float* W = (const float*)d_in[2];
  float* out     = (float*)d_out;

  dim3 grid(ROWS / (RPW * WVS));  // 768 blocks
  dim3 block(256);
  gat_fused_kernel<<<grid, block, 0, stream>>>(x, W, out);
}